// Round 2
// baseline (1995.351 us; speedup 1.0000x reference)
//
#include <hip/hip_runtime.h>
#include <hip/hip_bf16.h>

typedef __hip_bfloat16 bf16_t;
typedef __attribute__((ext_vector_type(8))) short short8;
typedef __attribute__((ext_vector_type(4))) float f32x4;

#define DEV_INLINE __device__ __forceinline__

constexpr int BB = 2, SS = 2048, DD = 4096, HH = 16, HDIM = 256;

DEV_INLINE void gll16(const void* g, void* l) {
  __builtin_amdgcn_global_load_lds((const __attribute__((address_space(1))) void*)g,
                                   (__attribute__((address_space(3))) void*)l,
                                   16, 0, 0);
}

DEV_INLINE f32x4 mfma_bf16(short8 a, short8 b, f32x4 c) {
  return __builtin_amdgcn_mfma_f32_16x16x32_bf16(a, b, c, 0, 0, 0);
}

// ---------- hidden_states fp32 -> bf16 ----------
__global__ void __launch_bounds__(256) xconv_kernel(const float* __restrict__ X,
                                                    bf16_t* __restrict__ Xb) {
  int i = (blockIdx.x * 256 + threadIdx.x) * 4;
  float4 v = *(const float4*)(X + i);
  ushort4 u;
  bf16_t h;
  h = __float2bfloat16(v.x); u.x = *(unsigned short*)&h;
  h = __float2bfloat16(v.y); u.y = *(unsigned short*)&h;
  h = __float2bfloat16(v.z); u.z = *(unsigned short*)&h;
  h = __float2bfloat16(v.w); u.w = *(unsigned short*)&h;
  *(ushort4*)(Xb + i) = u;
}

// ---------- weights fp32 (K,N) -> bf16 (N,K) transposed ----------
__global__ void __launch_bounds__(256) wtrans_kernel(
    const float* __restrict__ W0, const float* __restrict__ W1,
    const float* __restrict__ W2, const float* __restrict__ W3,
    bf16_t* __restrict__ T0, bf16_t* __restrict__ T1,
    bf16_t* __restrict__ T2, bf16_t* __restrict__ T3) {
  __shared__ float tile[64][65];
  const float* W;
  bf16_t* T;
  switch (blockIdx.z) {
    case 0: W = W0; T = T0; break;
    case 1: W = W1; T = T1; break;
    case 2: W = W2; T = T2; break;
    default: W = W3; T = T3; break;
  }
  int n0 = blockIdx.x * 64, k0 = blockIdx.y * 64;
  int tx = threadIdx.x & 63, ty = threadIdx.x >> 6;
#pragma unroll
  for (int r = 0; r < 64; r += 4)
    tile[r + ty][tx] = W[(size_t)(k0 + r + ty) * DD + n0 + tx];
  __syncthreads();
#pragma unroll
  for (int r = 0; r < 64; r += 4)
    T[(size_t)(n0 + r + ty) * DD + k0 + tx] = __float2bfloat16(tile[tx][r + ty]);
}

// ---------- 128x128 bf16 GEMM core: A (M,K) row-major, Bt (N,K) row-major ----------
template <class Epi>
DEV_INLINE void gemm128_core(const bf16_t* __restrict__ A, const bf16_t* __restrict__ Bt,
                             int Kdim, Epi epi) {
  __shared__ __align__(16) bf16_t As[128 * 32];
  __shared__ __align__(16) bf16_t Bs[128 * 32];
  const int tid = threadIdx.x;
  const int lane = tid & 63;
  const int w = tid >> 6;       // wave 0..3
  const int wm = w >> 1, wn = w & 1;
  const int m0 = blockIdx.y * 128;
  const int n0 = blockIdx.x * 128;
  const int lrow = lane & 15, lgrp = lane >> 4;

  f32x4 zero = {0.f, 0.f, 0.f, 0.f};
  f32x4 acc[4][4];
#pragma unroll
  for (int i = 0; i < 4; ++i)
#pragma unroll
    for (int j = 0; j < 4; ++j) acc[i][j] = zero;

  const int srow = lane >> 2;        // 0..15 (row within 16-row chunk)
  const int scol = (lane & 3) * 8;   // element offset (16B per lane)

  for (int k0 = 0; k0 < Kdim; k0 += 32) {
#pragma unroll
    for (int i = 0; i < 2; ++i) {
      int r = i * 64 + w * 16;      // wave-uniform row base
      gll16(A + (size_t)(m0 + r + srow) * Kdim + k0 + scol, As + r * 32);
      gll16(Bt + (size_t)(n0 + r + srow) * Kdim + k0 + scol, Bs + r * 32);
    }
    __syncthreads();
    short8 af[4], bfr[4];
#pragma unroll
    for (int i = 0; i < 4; ++i) {
      af[i]  = *(const short8*)(As + (wm * 64 + i * 16 + lrow) * 32 + lgrp * 8);
      bfr[i] = *(const short8*)(Bs + (wn * 64 + i * 16 + lrow) * 32 + lgrp * 8);
    }
#pragma unroll
    for (int i = 0; i < 4; ++i)
#pragma unroll
      for (int j = 0; j < 4; ++j)
        acc[i][j] = mfma_bf16(af[i], bfr[j], acc[i][j]);
    __syncthreads();
  }
  epi(acc, m0 + wm * 64, n0 + wn * 64, lrow, lgrp);
}

// ---------- QKV projection: C -> Q/K (B,H,S,HD) bf16, V -> (B,H,HD,S) bf16 ----------
__global__ void __launch_bounds__(256) qkv_gemm_kernel(
    const bf16_t* __restrict__ Xb,
    const bf16_t* __restrict__ Wqt, const bf16_t* __restrict__ Wkt, const bf16_t* __restrict__ Wvt,
    bf16_t* __restrict__ Qh, bf16_t* __restrict__ Kh, bf16_t* __restrict__ Vt) {
  const int z = blockIdx.z;
  const bf16_t* Bt = (z == 0) ? Wqt : (z == 1) ? Wkt : Wvt;
  gemm128_core(Xb, Bt, DD, [&](f32x4 (&acc)[4][4], int mb, int nb, int lrow, int lgrp) {
#pragma unroll
    for (int i = 0; i < 4; ++i) {
#pragma unroll
      for (int j = 0; j < 4; ++j) {
        int n = nb + j * 16 + lrow;
        int h = n >> 8, d = n & 255;
#pragma unroll
        for (int r = 0; r < 4; ++r) {
          int m = mb + i * 16 + lgrp * 4 + r;
          int b = m >> 11, s = m & 2047;
          bf16_t hv = __float2bfloat16(acc[i][j][r]);
          if (z == 2)
            Vt[((size_t)((b * HH + h) * HDIM + d)) * SS + s] = hv;
          else if (z == 1)
            Kh[((size_t)((b * HH + h) * SS + s)) * HDIM + d] = hv;
          else
            Qh[((size_t)((b * HH + h) * SS + s)) * HDIM + d] = hv;
        }
      }
    }
  });
}

// ---------- output projection: C fp32 row-major ----------
__global__ void __launch_bounds__(256) out_gemm_kernel(
    const bf16_t* __restrict__ Ab, const bf16_t* __restrict__ Wot,
    float* __restrict__ Cout) {
  gemm128_core(Ab, Wot, DD, [&](f32x4 (&acc)[4][4], int mb, int nb, int lrow, int lgrp) {
#pragma unroll
    for (int i = 0; i < 4; ++i)
#pragma unroll
      for (int j = 0; j < 4; ++j)
#pragma unroll
        for (int r = 0; r < 4; ++r)
          Cout[(size_t)(mb + i * 16 + lgrp * 4 + r) * DD + nb + j * 16 + lrow] = acc[i][j][r];
  });
}

// ---------- in-place interleaved RoPE on first 64 dims of Q and K ----------
__global__ void __launch_bounds__(256) rope_kernel(bf16_t* __restrict__ Qh,
                                                   bf16_t* __restrict__ Kh,
                                                   const int* __restrict__ pos) {
  int t = blockIdx.x * 256 + threadIdx.x;       // 0 .. 2*B*H*S*32-1
  int buf = t >> 21;                            // B*H*S*32 = 2^21
  int rem = t & ((1 << 21) - 1);
  int row = rem >> 5;                           // bh*S + s
  int i = rem & 31;                             // pair index
  int bh = row >> 11;
  int s = row & 2047;
  int b = bh >> 4;
  int p = pos[b * SS + s];
  float inv = exp2f(-(float)i * 0.4152410118609203f);  // log2(10000)/32
  float ang = (float)p * inv;
  float sn, cs;
  __sincosf(ang, &sn, &cs);
  bf16_t* ptr = (buf ? Kh : Qh) + (size_t)row * HDIM + 2 * i;
  float x1 = __bfloat162float(ptr[0]);
  float x2 = __bfloat162float(ptr[1]);
  ptr[0] = __float2bfloat16(x1 * cs - x2 * sn);
  ptr[1] = __float2bfloat16(x2 * cs + x1 * sn);
}

// ---------- causal flash attention ----------
__global__ void __launch_bounds__(256) attn_kernel(const bf16_t* __restrict__ Qh,
                                                   const bf16_t* __restrict__ Kh,
                                                   const bf16_t* __restrict__ Vt,
                                                   bf16_t* __restrict__ Ab) {
  __shared__ __align__(16) bf16_t Plds[4][16][64];
  const int lane = threadIdx.x & 63;
  const int w = threadIdx.x >> 6;
  const int lrow = lane & 15, lgrp = lane >> 4;
  const int q0 = blockIdx.x * 64;
  const int bh = blockIdx.y;
  const int b = bh >> 4, h = bh & 15;
  const bf16_t* Qb = Qh + (size_t)bh * SS * HDIM;
  const bf16_t* Kb = Kh + (size_t)bh * SS * HDIM;
  const bf16_t* Vb = Vt + (size_t)bh * HDIM * SS;

  short8 qf[8];
#pragma unroll
  for (int ks = 0; ks < 8; ++ks)
    qf[ks] = *(const short8*)(Qb + (size_t)(q0 + w * 16 + lrow) * HDIM + ks * 32 + lgrp * 8);

  f32x4 zero = {0.f, 0.f, 0.f, 0.f};
  f32x4 o[16];
#pragma unroll
  for (int i = 0; i < 16; ++i) o[i] = zero;
  float mi[4], li[4];
#pragma unroll
  for (int r = 0; r < 4; ++r) { mi[r] = -3.0e38f; li[r] = 0.f; }

  const int ntk = blockIdx.x + 1;
  for (int kt = 0; kt < ntk; ++kt) {
    const int k0 = kt * 64;
    f32x4 sc[4];
#pragma unroll
    for (int nf = 0; nf < 4; ++nf) sc[nf] = zero;
#pragma unroll
    for (int ks = 0; ks < 8; ++ks) {
#pragma unroll
      for (int nf = 0; nf < 4; ++nf) {
        short8 kf = *(const short8*)(Kb + (size_t)(k0 + nf * 16 + lrow) * HDIM + ks * 32 + lgrp * 8);
        sc[nf] = mfma_bf16(qf[ks], kf, sc[nf]);
      }
    }
    const bool diag = (kt == (int)blockIdx.x);
#pragma unroll
    for (int nf = 0; nf < 4; ++nf)
#pragma unroll
      for (int r = 0; r < 4; ++r) {
        float v = sc[nf][r] * 0.0625f;    // 1/sqrt(HD)
        if (diag && (nf * 16 + lrow > w * 16 + lgrp * 4 + r)) v = -3.0e38f;
        sc[nf][r] = v;
      }
    float pm[4], al[4], rs[4];
#pragma unroll
    for (int r = 0; r < 4; ++r) {
      float v = fmaxf(fmaxf(sc[0][r], sc[1][r]), fmaxf(sc[2][r], sc[3][r]));
#pragma unroll
      for (int off = 1; off < 16; off <<= 1) v = fmaxf(v, __shfl_xor(v, off));
      pm[r] = v;
    }
#pragma unroll
    for (int r = 0; r < 4; ++r) {
      float mnew = fmaxf(mi[r], pm[r]);
      al[r] = exp2f((mi[r] - mnew) * 1.44269504f);
      mi[r] = mnew;
      rs[r] = 0.f;
    }
#pragma unroll
    for (int nf = 0; nf < 4; ++nf)
#pragma unroll
      for (int r = 0; r < 4; ++r) {
        float p = exp2f((sc[nf][r] - mi[r]) * 1.44269504f);
        sc[nf][r] = p;
        rs[r] += p;
      }
#pragma unroll
    for (int r = 0; r < 4; ++r) {
      float v = rs[r];
#pragma unroll
      for (int off = 1; off < 16; off <<= 1) v += __shfl_xor(v, off);
      li[r] = li[r] * al[r] + v;
    }
#pragma unroll
    for (int i = 0; i < 16; ++i) {
      f32x4 t = o[i];
      t[0] *= al[0]; t[1] *= al[1]; t[2] *= al[2]; t[3] *= al[3];
      o[i] = t;
    }
    // P (D-layout) -> LDS -> A-fragment layout (per-wave private buffer)
#pragma unroll
    for (int nf = 0; nf < 4; ++nf)
#pragma unroll
      for (int r = 0; r < 4; ++r)
        Plds[w][lgrp * 4 + r][nf * 16 + lrow] = __float2bfloat16(sc[nf][r]);
    short8 pa[2];
#pragma unroll
    for (int ks2 = 0; ks2 < 2; ++ks2)
      pa[ks2] = *(const short8*)(&Plds[w][lrow][ks2 * 32 + lgrp * 8]);
#pragma unroll
    for (int ks2 = 0; ks2 < 2; ++ks2)
#pragma unroll
      for (int nf2 = 0; nf2 < 16; ++nf2) {
        short8 vf = *(const short8*)(Vb + (size_t)(nf2 * 16 + lrow) * SS + k0 + ks2 * 32 + lgrp * 8);
        o[nf2] = mfma_bf16(pa[ks2], vf, o[nf2]);
      }
  }
  float inv[4];
#pragma unroll
  for (int r = 0; r < 4; ++r) inv[r] = 1.f / li[r];
#pragma unroll
  for (int nf2 = 0; nf2 < 16; ++nf2)
#pragma unroll
    for (int r = 0; r < 4; ++r) {
      int q = q0 + w * 16 + lgrp * 4 + r;
      int d = nf2 * 16 + lrow;
      Ab[(size_t)(b * SS + q) * DD + h * HDIM + d] = __float2bfloat16(o[nf2][r] * inv[r]);
    }
}

extern "C" void kernel_launch(void* const* d_in, const int* in_sizes, int n_in,
                              void* d_out, int out_size, void* d_ws, size_t ws_size,
                              hipStream_t stream) {
  const float* X  = (const float*)d_in[0];
  const int* pos  = (const int*)d_in[1];
  const float* Wq = (const float*)d_in[2];
  const float* Wk = (const float*)d_in[3];
  const float* Wv = (const float*)d_in[4];
  const float* Wo = (const float*)d_in[5];
  float* Out = (float*)d_out;
  char* ws = (char*)d_ws;

  const size_t SZ = (size_t)4096 * 4096 * 2;  // 32MB: one bf16 4096x4096 matrix
  bf16_t* Xb  = (bf16_t*)(ws);
  bf16_t* Wqt = (bf16_t*)(ws + 1 * SZ);
  bf16_t* Wkt = (bf16_t*)(ws + 2 * SZ);
  bf16_t* Wvt = (bf16_t*)(ws + 3 * SZ);
  bf16_t* Wot = (bf16_t*)(ws + 4 * SZ);
  bf16_t* Qh  = (bf16_t*)(ws + 5 * SZ);
  bf16_t* Kh  = (bf16_t*)(ws + 6 * SZ);
  bf16_t* Vt  = (bf16_t*)(ws + 7 * SZ);
  bf16_t* Ab  = Xb;  // Xb is dead after qkv_gemm; reuse for attention output

  xconv_kernel<<<16384, 256, 0, stream>>>(X, Xb);
  wtrans_kernel<<<dim3(64, 64, 4), 256, 0, stream>>>(Wq, Wk, Wv, Wo, Wqt, Wkt, Wvt, Wot);
  qkv_gemm_kernel<<<dim3(32, 32, 3), 256, 0, stream>>>(Xb, Wqt, Wkt, Wvt, Qh, Kh, Vt);
  rope_kernel<<<16384, 256, 0, stream>>>(Qh, Kh, pos);
  attn_kernel<<<dim3(32, 32), 256, 0, stream>>>(Qh, Kh, Vt, Ab);
  out_gemm_kernel<<<dim3(32, 32), 256, 0, stream>>>(Ab, Wot, Out);
}